// Round 10
// baseline (1628.084 us; speedup 1.0000x reference)
//
#include <hip/hip_runtime.h>
#include <hip/hip_bf16.h>

#define T_TOK 8192
#define H_DIM 2048
#define NE    16
#define TOPK  4
#define IMOE  1408
#define ISH   5632
#define TK    (T_TOK*TOPK)
#define MAXT256 ((TK/256)+NE)

typedef __bf16 bf16;
typedef __attribute__((ext_vector_type(8)))  __bf16 bf16x8;
typedef __attribute__((ext_vector_type(4)))  float  f32x4;
typedef __attribute__((ext_vector_type(16))) float  f32x16;

__device__ __forceinline__ void gload_lds16(const bf16* g, bf16* l) {
  __builtin_amdgcn_global_load_lds((const __attribute__((address_space(1))) void*)g,
                                   (__attribute__((address_space(3))) void*)l, 16, 0, 0);
}
#define MEMFENCE asm volatile("" ::: "memory")
#define BARRIER  do { MEMFENCE; __builtin_amdgcn_s_barrier(); MEMFENCE; } while (0)
#define VMCNT4   asm volatile("s_waitcnt vmcnt(4)" ::: "memory")

// ---------------- fp32 [R][C] -> bf16 [C'][R] transpose, 64x64 tiles, vectorized.
__global__ __launch_bounds__(256) void cvt_transpose64(const float* __restrict__ in,
                                                       bf16* __restrict__ out,
                                                       int R, int C,
                                                       size_t strideIn, size_t strideOut,
                                                       int split, int base_off) {
  __shared__ float tile[64][65];
  const float* inm = in + (size_t)blockIdx.z * strideIn;
  bf16* outm = out + (size_t)blockIdx.z * strideOut;
  int c0 = blockIdx.x * 64, r0 = blockIdx.y * 64;
  int tid = threadIdx.x;
  int rr = tid >> 4, cc4 = (tid & 15) * 4;
  #pragma unroll
  for (int i = 0; i < 4; ++i) {
    f32x4 v = __builtin_nontemporal_load(
        (const f32x4*)&inm[(size_t)(r0 + rr + i * 16) * C + c0 + cc4]);
    tile[rr + i * 16][cc4 + 0] = v.x;
    tile[rr + i * 16][cc4 + 1] = v.y;
    tile[rr + i * 16][cc4 + 2] = v.z;
    tile[rr + i * 16][cc4 + 3] = v.w;
  }
  __syncthreads();
  int r8 = (tid & 7) * 8;
  #pragma unroll
  for (int i = 0; i < 2; ++i) {
    int c = (tid >> 3) + i * 32;
    int co = c0 + c;
    int orow;
    if (split < 0) orow = co;
    else {
      int cl = co, o = base_off;
      if (cl >= split) { cl -= split; o += 128; }
      orow = ((cl >> 7) << 8) + o + (cl & 127);
    }
    bf16x8 v;
    #pragma unroll
    for (int j = 0; j < 8; ++j) v[j] = (bf16)tile[r8 + j][c];
    *(bf16x8*)&outm[(size_t)orow * R + r0 + r8] = v;
  }
}

// ---------------- zero small counters
__global__ void init_kernel(int* counts, int* fill) {
  int i = threadIdx.x;
  if (i < NE) { counts[i] = 0; fill[i] = 0; }
}

// ---------------- router: wave-per-token, fp64 logits, lane-parallel top-4, no atomics
__global__ __launch_bounds__(256) void router_kernel(const float* __restrict__ X,
                                                     const float* __restrict__ Wr,
                                                     const float* __restrict__ wgate,
                                                     bf16* __restrict__ Xbf,
                                                     float* __restrict__ topk_w,
                                                     int* __restrict__ topk_idx,
                                                     float* __restrict__ gate_sig) {
  const int wv = threadIdx.x >> 6, lane = threadIdx.x & 63;
  const int t = blockIdx.x * 4 + wv;
  const float* x = X + (size_t)t * H_DIM;
  float xf[32];
  #pragma unroll
  for (int j = 0; j < 32; ++j) xf[j] = x[j * 64 + lane];
  #pragma unroll
  for (int j = 0; j < 32; ++j) Xbf[(size_t)t * H_DIM + j * 64 + lane] = (bf16)xf[j];

  double lg = 0.0;
  for (int e = 0; e < NE + 1; ++e) {
    const float* w = (e < NE) ? (Wr + (size_t)e * H_DIM) : wgate;
    double s0 = 0.0, s1 = 0.0;
    #pragma unroll
    for (int j = 0; j < 32; j += 2) {
      s0 += (double)xf[j] * (double)w[j * 64 + lane];
      s1 += (double)xf[j + 1] * (double)w[(j + 1) * 64 + lane];
    }
    double s = s0 + s1;
    #pragma unroll
    for (int off = 32; off; off >>= 1) s += __shfl_xor(s, off);
    if (lane == e) lg = s;
  }

  double v = (lane < NE) ? lg : -1e300;
  double m = v;
  #pragma unroll
  for (int off = 32; off; off >>= 1) m = fmax(m, __shfl_xor(m, off));
  double ev = (lane < NE) ? exp(v - m) : 0.0;
  double den = ev;
  #pragma unroll
  for (int off = 32; off; off >>= 1) den += __shfl_xor(den, off);

  double vv = v;
  int widx = 0; double wval = 0.0;
  for (int k = 0; k < TOPK; ++k) {
    double bv = vv; int bi = lane;
    #pragma unroll
    for (int off = 32; off; off >>= 1) {
      double ov = __shfl_xor(bv, off);
      int oi = __shfl_xor(bi, off);
      if (ov > bv || (ov == bv && oi < bi)) { bv = ov; bi = oi; }
    }
    double evb = __shfl(ev, bi);
    if (lane == k) { widx = bi; wval = evb / den; }
    if (lane == bi) vv = -1e300;
  }
  if (lane < TOPK) {
    topk_idx[t * TOPK + lane] = widx;
    topk_w[t * TOPK + lane] = (float)wval;
  }
  if (lane == NE) gate_sig[t] = (float)(1.0 / (1.0 + exp(-lg)));
}

// ---------------- histogram (LDS-local, 16 atomics/block)
__global__ __launch_bounds__(256) void hist_kernel(const int* __restrict__ tidx,
                                                   int* __restrict__ counts) {
  __shared__ int h[NE];
  if (threadIdx.x < NE) h[threadIdx.x] = 0;
  __syncthreads();
  int gid = blockIdx.x * 256 + threadIdx.x;
  atomicAdd(&h[tidx[gid]], 1);
  __syncthreads();
  if (threadIdx.x < NE) atomicAdd(&counts[threadIdx.x], h[threadIdx.x]);
}

// ---------------- prefix scan + 256-row grouped tile table
__global__ void scan_kernel(const int* __restrict__ counts, int* __restrict__ offs,
                            int* __restrict__ fill, int* __restrict__ ttab,
                            int* __restrict__ ntl) {
  if (threadIdx.x != 0) return;
  int off = 0;
  for (int e = 0; e < NE; ++e) { offs[e] = off; off += counts[e]; fill[e] = 0; }
  offs[NE] = off;
  int n = 0;
  for (int e = 0; e < NE; ++e) {
    int cnt = counts[e], end_ = offs[e] + cnt;
    for (int m = 0; m < cnt; m += 256) {
      ttab[n * 3 + 0] = e;
      ttab[n * 3 + 1] = offs[e] + m;
      ttab[n * 3 + 2] = end_;
      ++n;
    }
  }
  *ntl = n;
}

// ---------------- scatter: hierarchical rank (ballot) + 16 atomics/block
__global__ __launch_bounds__(256) void scatter_kernel(const int* __restrict__ topk_idx,
                                                      const int* __restrict__ offs,
                                                      int* __restrict__ fill,
                                                      int* __restrict__ row_token,
                                                      int* __restrict__ row_pos) {
  __shared__ int wc[4][NE];
  __shared__ int wbase[4][NE];
  __shared__ int bbase[NE];
  const int tid = threadIdx.x, wv = tid >> 6, lane = tid & 63;
  const int gid = blockIdx.x * 256 + tid;
  const int e = topk_idx[gid];
  int rank = 0;
  #pragma unroll
  for (int ex = 0; ex < NE; ++ex) {
    unsigned long long b = __ballot(e == ex);
    if (e == ex) rank = __popcll(b & ((1ull << lane) - 1));
    if (lane == 0) wc[wv][ex] = __popcll(b);
  }
  __syncthreads();
  if (tid < NE) {
    int s = 0;
    #pragma unroll
    for (int w = 0; w < 4; ++w) { wbase[w][tid] = s; s += wc[w][tid]; }
    bbase[tid] = atomicAdd(&fill[tid], s);
  }
  __syncthreads();
  int pos = offs[e] + bbase[e] + wbase[wv][e] + rank;
  row_token[pos] = gid >> 2;
  row_pos[gid] = pos;
}

// 8 MFMA of 32x32x16 per cluster; ks-outer/m-inner alternates accumulators
// so same-acc dependent MFMAs are 2 issue slots (~16 cyc) apart.
__device__ __forceinline__ void mfma_cluster32(f32x16 (&a)[2], bf16x8 (&A)[2][4],
                                               bf16x8 (&B)[4]) {
  __builtin_amdgcn_s_setprio(1);
  #pragma unroll
  for (int ks = 0; ks < 4; ++ks)
    #pragma unroll
    for (int m = 0; m < 2; ++m)
      a[m] = __builtin_amdgcn_mfma_f32_32x32x16_bf16(A[m][ks], B[ks], a[m], 0, 0, 0);
  __builtin_amdgcn_s_setprio(0);
}

struct GArgs {
  const bf16* A; const bf16* B; bf16* C;
  const int* row_token; const int* tile_tab; const int* n_tiles;
  size_t strideB;
  int lda, Ktot, ldc, Mdense, gx, gy;
};

// ---------------- 256x256 bf16 MFMA GEMM (32x32x16 fragments), R8 wait schedule.
// Two independent GEMMs merged per launch (block-id split) to amortize tails.
__global__ __launch_bounds__(512, 2) void gemm256(GArgs ga, GArgs gb, int nblk0,
                                                  int fuse_swiglu) {
  GArgs g; int id;
  if ((int)blockIdx.x < nblk0) { g = ga; id = blockIdx.x; }
  else { g = gb; id = blockIdx.x - nblk0; }
  const int gx = g.gx, gy = g.gy;
  int mt, nt;
  if ((gx & 7) == 0) {          // mt-residue octave sweep (R8-best locality map)
    int oct = id / (8 * gy);
    int rem = id - oct * 8 * gy;
    mt = oct * 8 + (rem & 7);
    nt = rem >> 3;
  } else {
    mt = id % gx;
    nt = id / gx;
  }

  int e, row_start, row_end;
  if (g.tile_tab) {
    if (mt >= *g.n_tiles) return;
    e = g.tile_tab[mt * 3 + 0];
    row_start = g.tile_tab[mt * 3 + 1];
    row_end = g.tile_tab[mt * 3 + 2];
  } else {
    e = 0; row_start = mt * 256; row_end = g.Mdense;
  }
  const bf16* Ap = g.A;
  const bf16* Bp = g.B + (size_t)e * g.strideB;
  const int lda = g.lda, Ktot = g.Ktot, ldc = g.ldc;
  bf16* C = g.C;

  __shared__ bf16 smA[2][2][8192];   // [buf][half][128*64]
  __shared__ bf16 smB[2][2][8192];

  const int tid = threadIdx.x;
  const int wave = tid >> 6;
  const int lane = tid & 63;

  unsigned aoff[2][2], boff[2][2];
  {
    int csrc = (((tid & 7) ^ ((tid >> 3) & 7)) << 3);
    #pragma unroll
    for (int h = 0; h < 2; ++h)
      #pragma unroll
      for (int j = 0; j < 2; ++j) {
        int rho = j * 64 + (tid >> 3);
        int r = row_start + h * 128 + rho;
        if (r > row_end - 1) r = row_end - 1;
        int sr = g.row_token ? g.row_token[r] : r;
        aoff[h][j] = (unsigned)sr * (unsigned)lda + (unsigned)csrc;
        boff[h][j] = (unsigned)(nt * 256 + h * 128 + rho) * (unsigned)Ktot + (unsigned)csrc;
      }
  }

  auto STAGE_A = [&](int bufi, int h, int tt) {
    gload_lds16(Ap + (size_t)(aoff[h][0] + (unsigned)tt * 64u), &smA[bufi][h][wave << 9]);
    gload_lds16(Ap + (size_t)(aoff[h][1] + (unsigned)tt * 64u), &smA[bufi][h][4096 + (wave << 9)]);
  };
  auto STAGE_B = [&](int bufi, int h, int tt) {
    gload_lds16(Bp + (size_t)(boff[h][0] + (unsigned)tt * 64u), &smB[bufi][h][wave << 9]);
    gload_lds16(Bp + (size_t)(boff[h][1] + (unsigned)tt * 64u), &smB[bufi][h][4096 + (wave << 9)]);
  };

  // 32x32x16 fragment geometry: A row = lane&31, k-group = lane>>5;
  // wave grid: rows (wave>>2)*64 (+m*32), cols (wave&3)*32 per quadrant-half.
  const int warow = ((wave >> 2) << 6) + (lane & 31);
  const int wbrow = ((wave & 3) << 5) + (lane & 31);
  const int q5 = lane >> 5;
  auto LDA_ = [&](int bufi, int h, int m, int ks) -> bf16x8 {
    int row = warow + m * 32;
    int c = (ks * 2 + q5) ^ (row & 7);
    return *(const bf16x8*)&smA[bufi][h][row * 64 + c * 8];
  };
  auto LDB_ = [&](int bufi, int h, int ks) -> bf16x8 {
    int c = (ks * 2 + q5) ^ (wbrow & 7);
    return *(const bf16x8*)&smB[bufi][h][wbrow * 64 + c * 8];
  };

  f32x16 acc[4][2];   // [quadrant][m]
  #pragma unroll
  for (int q = 0; q < 4; ++q)
    #pragma unroll
    for (int m = 0; m < 2; ++m) acc[q][m] = (f32x16)(0.0f);

  bf16x8 Ar[2][4], Br0[4], Br1[4];

#define RD_A(BUF, H) do { \
    _Pragma("unroll") for (int m_ = 0; m_ < 2; ++m_) \
      _Pragma("unroll") for (int k_ = 0; k_ < 4; ++k_) \
        Ar[m_][k_] = LDA_(BUF, H, m_, k_); } while (0)
#define RD_B(BUF, H, DST) do { \
    _Pragma("unroll") for (int k_ = 0; k_ < 4; ++k_) \
      DST[k_] = LDB_(BUF, H, k_); } while (0)

#define DO_TILE(CB, NB, TS) do { \
    /* f1: q0=(A0,B0); stage A0(NB); post-MFMA wait drains B1(CB) for f2 */ \
    RD_A(CB, 0); RD_B(CB, 0, Br0); \
    STAGE_A(NB, 0, TS); \
    BARRIER; \
    mfma_cluster32(acc[0], Ar, Br0); \
    VMCNT4; \
    BARRIER; \
    /* f2: q1=(A0,B1); stage B0(NB); post-MFMA wait drains A1(CB) for f3 */ \
    RD_B(CB, 1, Br1); \
    STAGE_B(NB, 0, TS); \
    BARRIER; \
    mfma_cluster32(acc[1], Ar, Br1); \
    VMCNT4; \
    BARRIER; \
    /* f3: q2=(A1,B1); stage B1(NB) */ \
    RD_A(CB, 1); \
    STAGE_B(NB, 1, TS); \
    BARRIER; \
    mfma_cluster32(acc[2], Ar, Br1); \
    BARRIER; \
    /* f4: q3=(A1,B0); stage A1(NB); post-MFMA wait drains A0,B0(NB) for next f1 */ \
    STAGE_A(NB, 1, TS); \
    mfma_cluster32(acc[3], Ar, Br0); \
    VMCNT4; \
    BARRIER; \
  } while (0)

  STAGE_A(0, 0, 0); STAGE_B(0, 0, 0); STAGE_B(0, 1, 0); STAGE_A(0, 1, 0);
  VMCNT4; BARRIER;

  const int nk = Ktot >> 6;
  for (int it = 0; it < nk; it += 2) {
    const int ts1 = it + 1;
    const int ts2 = (it + 2 < nk) ? it + 2 : it + 1;
    DO_TILE(0, 1, ts1);
    DO_TILE(1, 0, ts2);
  }
#undef DO_TILE
#undef RD_A
#undef RD_B

  // Epilogue. C/D 32x32: col=lane&31, row=(reg&3)+8*(reg>>2)+4*(lane>>5) [m74/m101]
  const int er = (lane >> 5) << 2;
  if (fuse_swiglu) {
    const int cb0 = nt * 128 + ((wave & 3) << 5) + (lane & 31);
    #pragma unroll
    for (int qi = 0; qi < 2; ++qi) {
      const int qg = qi ? 3 : 0, qu = qi ? 2 : 1;
      int rb = row_start + qi * 128 + ((wave >> 2) << 6) + er;
      #pragma unroll
      for (int m = 0; m < 2; ++m)
        #pragma unroll
        for (int reg = 0; reg < 16; ++reg) {
          int r = rb + m * 32 + (reg & 3) + ((reg >> 2) << 3);
          if (r < row_end) {
            float gg = acc[qg][m][reg];
            float uu = acc[qu][m][reg];
            float s = gg / (1.f + __expf(-gg));
            C[(size_t)r * ldc + cb0] = (bf16)(s * uu);
          }
        }
    }
  } else {
    const int qr[4] = {0, 0, 1, 1}, qc[4] = {0, 1, 1, 0};
    #pragma unroll
    for (int q = 0; q < 4; ++q) {
      int rb = row_start + qr[q] * 128 + ((wave >> 2) << 6) + er;
      int cb0 = nt * 256 + qc[q] * 128 + ((wave & 3) << 5) + (lane & 31);
      #pragma unroll
      for (int m = 0; m < 2; ++m)
        #pragma unroll
        for (int reg = 0; reg < 16; ++reg) {
          int r = rb + m * 32 + (reg & 3) + ((reg >> 2) << 3);
          if (r < row_end) C[(size_t)r * ldc + cb0] = (bf16)acc[q][m][reg];
        }
    }
  }
}

// ---------------- combine
__global__ __launch_bounds__(256) void combine_kernel(const float* __restrict__ topk_w,
                                                      const int* __restrict__ row_pos,
                                                      const bf16* __restrict__ eout,
                                                      const bf16* __restrict__ shout,
                                                      const float* __restrict__ gate_sig,
                                                      float* __restrict__ out) {
  int t = blockIdx.x;
  float w0 = topk_w[t * 4 + 0], w1 = topk_w[t * 4 + 1];
  float w2 = topk_w[t * 4 + 2], w3 = topk_w[t * 4 + 3];
  size_t p0 = (size_t)row_pos[t * 4 + 0] * H_DIM;
  size_t p1 = (size_t)row_pos[t * 4 + 1] * H_DIM;
  size_t p2 = (size_t)row_pos[t * 4 + 2] * H_DIM;
  size_t p3 = (size_t)row_pos[t * 4 + 3] * H_DIM;
  float g = gate_sig[t];
  size_t tb = (size_t)t * H_DIM;
  size_t hb = (size_t)threadIdx.x * 8;
  bf16x8 a0 = *(const bf16x8*)&eout[p0 + hb];
  bf16x8 a1 = *(const bf16x8*)&eout[p1 + hb];
  bf16x8 a2 = *(const bf16x8*)&eout[p2 + hb];
  bf16x8 a3 = *(const bf16x8*)&eout[p3 + hb];
  bf16x8 sh = *(const bf16x8*)&shout[tb + hb];
  float r[8];
  #pragma unroll
  for (int j = 0; j < 8; ++j)
    r[j] = w0 * (float)a0[j] + w1 * (float)a1[j] + w2 * (float)a2[j]
         + w3 * (float)a3[j] + g * (float)sh[j];
  float4 o0 = {r[0], r[1], r[2], r[3]}, o1 = {r[4], r[5], r[6], r[7]};
  *(float4*)&out[tb + hb] = o0;
  *(float4*)&out[tb + hb + 4] = o1;
}

extern "C" void kernel_launch(void* const* d_in, const int* in_sizes, int n_in,
                              void* d_out, int out_size, void* d_ws, size_t ws_size,
                              hipStream_t stream) {
  const float* X   = (const float*)d_in[0];
  const float* Wr  = (const float*)d_in[1];
  const float* Wgu = (const float*)d_in[2];
  const float* Wd  = (const float*)d_in[3];
  const float* Wsg = (const float*)d_in[4];
  const float* Wsu = (const float*)d_in[5];
  const float* Wsd = (const float*)d_in[6];
  const float* Wge = (const float*)d_in[7];
  float* out = (float*)d_out;

  size_t off = 0;
  auto alloc = [&](size_t bytes) -> void* {
    void* p = (char*)d_ws + off;
    off += (bytes + 255) & ~(size_t)255;
    return p;
  };
  bf16* Xbf    = (bf16*)alloc((size_t)T_TOK * H_DIM * 2);
  bf16* WguT   = (bf16*)alloc((size_t)NE * 2 * IMOE * H_DIM * 2);
  bf16* WdT    = (bf16*)alloc((size_t)NE * H_DIM * IMOE * 2);
  bf16* WsguT  = (bf16*)alloc((size_t)2 * ISH * H_DIM * 2);
  bf16* WsdT   = (bf16*)alloc((size_t)H_DIM * ISH * 2);
  bf16* act    = (bf16*)alloc((size_t)TK * IMOE * 2);
  bf16* act_sh = (bf16*)alloc((size_t)T_TOK * ISH * 2);
  bf16* eout   = (bf16*)alloc((size_t)TK * H_DIM * 2);
  bf16* shout  = (bf16*)alloc((size_t)T_TOK * H_DIM * 2);
  float* tw    = (float*)alloc((size_t)T_TOK * TOPK * 4);
  int*   tidx  = (int*)alloc((size_t)T_TOK * TOPK * 4);
  float* gsig  = (float*)alloc((size_t)T_TOK * 4);
  int*   counts= (int*)alloc(64);
  int*   offs  = (int*)alloc(128);
  int*   fill  = (int*)alloc(64);
  int*   rowtok= (int*)alloc((size_t)TK * 4);
  int*   rowpos= (int*)alloc((size_t)TK * 4);
  int*   ttab  = (int*)alloc((size_t)MAXT256 * 3 * 4);
  int*   ntl   = (int*)alloc(64);
  if (off > ws_size) return;

  init_kernel<<<1, 32, 0, stream>>>(counts, fill);

  cvt_transpose64<<<dim3(H_DIM / 64, ISH / 64, 1), 256, 0, stream>>>(
      Wsd, WsdT, ISH, H_DIM, 0, 0, -1, 0);
  cvt_transpose64<<<dim3(ISH / 64, H_DIM / 64, 1), 256, 0, stream>>>(
      Wsg, WsguT, H_DIM, ISH, 0, 0, ISH, 0);
  cvt_transpose64<<<dim3(ISH / 64, H_DIM / 64, 1), 256, 0, stream>>>(
      Wsu, WsguT, H_DIM, ISH, 0, 0, ISH, 128);
  cvt_transpose64<<<dim3(H_DIM / 64, IMOE / 64, NE), 256, 0, stream>>>(
      Wd, WdT, IMOE, H_DIM, (size_t)IMOE * H_DIM, (size_t)IMOE * H_DIM, -1, 0);
  cvt_transpose64<<<dim3(2 * IMOE / 64, H_DIM / 64, NE), 256, 0, stream>>>(
      Wgu, WguT, H_DIM, 2 * IMOE, (size_t)H_DIM * 2 * IMOE, (size_t)H_DIM * 2 * IMOE, IMOE, 0);

  router_kernel<<<T_TOK / 4, 256, 0, stream>>>(X, Wr, Wge, Xbf, tw, tidx, gsig);
  hist_kernel<<<TK / 256, 256, 0, stream>>>(tidx, counts);
  scan_kernel<<<1, 64, 0, stream>>>(counts, offs, fill, ttab, ntl);
  scatter_kernel<<<TK / 256, 256, 0, stream>>>(tidx, offs, fill, rowtok, rowpos);

  // Launch 1 (fused swiglu): grouped gate_up  ||  dense shared gate_up
  GArgs g1;
  g1.A = Xbf; g1.B = WguT; g1.C = act;
  g1.row_token = rowtok; g1.tile_tab = ttab; g1.n_tiles = ntl;
  g1.strideB = (size_t)2 * IMOE * H_DIM;
  g1.lda = H_DIM; g1.Ktot = H_DIM; g1.ldc = IMOE; g1.Mdense = 0;
  g1.gx = MAXT256; g1.gy = 2 * IMOE / 256;          // 144 x 11
  GArgs gsg;
  gsg.A = Xbf; gsg.B = WsguT; gsg.C = act_sh;
  gsg.row_token = nullptr; gsg.tile_tab = nullptr; gsg.n_tiles = nullptr;
  gsg.strideB = 0;
  gsg.lda = H_DIM; gsg.Ktot = H_DIM; gsg.ldc = ISH; gsg.Mdense = T_TOK;
  gsg.gx = T_TOK / 256; gsg.gy = 2 * ISH / 256;     // 32 x 44
  int nb1 = g1.gx * g1.gy;
  gemm256<<<nb1 + gsg.gx * gsg.gy, 512, 0, stream>>>(g1, gsg, nb1, 1);

  // Launch 2 (plain): grouped down  ||  dense shared down
  GArgs g2;
  g2.A = act; g2.B = WdT; g2.C = eout;
  g2.row_token = nullptr; g2.tile_tab = ttab; g2.n_tiles = ntl;
  g2.strideB = (size_t)H_DIM * IMOE;
  g2.lda = IMOE; g2.Ktot = IMOE; g2.ldc = H_DIM; g2.Mdense = 0;
  g2.gx = MAXT256; g2.gy = H_DIM / 256;             // 144 x 8
  GArgs gsd;
  gsd.A = act_sh; gsd.B = WsdT; gsd.C = shout;
  gsd.row_token = nullptr; gsd.tile_tab = nullptr; gsd.n_tiles = nullptr;
  gsd.strideB = 0;
  gsd.lda = ISH; gsd.Ktot = ISH; gsd.ldc = H_DIM; gsd.Mdense = T_TOK;
  gsd.gx = T_TOK / 256; gsd.gy = H_DIM / 256;       // 32 x 8
  int nb2 = g2.gx * g2.gy;
  gemm256<<<nb2 + gsd.gx * gsd.gy, 512, 0, stream>>>(g2, gsd, nb2, 0);

  combine_kernel<<<T_TOK, 256, 0, stream>>>(tw, rowpos, eout, shout, gsig, out);
}

// Round 11
// 1445.357 us; speedup vs baseline: 1.1264x; 1.1264x over previous
//
#include <hip/hip_runtime.h>
#include <hip/hip_bf16.h>

#define T_TOK 8192
#define H_DIM 2048
#define NE    16
#define TOPK  4
#define IMOE  1408
#define ISH   5632
#define TK    (T_TOK*TOPK)
#define MAXT256 ((TK/256)+NE)

typedef __bf16 bf16;
typedef __attribute__((ext_vector_type(8))) __bf16 bf16x8;
typedef __attribute__((ext_vector_type(4))) float  f32x4;

__device__ __forceinline__ void gload_lds16(const bf16* g, bf16* l) {
  __builtin_amdgcn_global_load_lds((const __attribute__((address_space(1))) void*)g,
                                   (__attribute__((address_space(3))) void*)l, 16, 0, 0);
}
#define MEMFENCE asm volatile("" ::: "memory")
#define BARRIER  do { MEMFENCE; __builtin_amdgcn_s_barrier(); MEMFENCE; } while (0)
#define VMCNT4   asm volatile("s_waitcnt vmcnt(4)" ::: "memory")

// ---------------- fp32 [R][C] -> bf16 [C'][R] transpose, 64x64 tiles, vectorized.
__global__ __launch_bounds__(256) void cvt_transpose64(const float* __restrict__ in,
                                                       bf16* __restrict__ out,
                                                       int R, int C,
                                                       size_t strideIn, size_t strideOut,
                                                       int split, int base_off) {
  __shared__ float tile[64][65];
  const float* inm = in + (size_t)blockIdx.z * strideIn;
  bf16* outm = out + (size_t)blockIdx.z * strideOut;
  int c0 = blockIdx.x * 64, r0 = blockIdx.y * 64;
  int tid = threadIdx.x;
  int rr = tid >> 4, cc4 = (tid & 15) * 4;
  #pragma unroll
  for (int i = 0; i < 4; ++i) {
    f32x4 v = __builtin_nontemporal_load(
        (const f32x4*)&inm[(size_t)(r0 + rr + i * 16) * C + c0 + cc4]);
    tile[rr + i * 16][cc4 + 0] = v.x;
    tile[rr + i * 16][cc4 + 1] = v.y;
    tile[rr + i * 16][cc4 + 2] = v.z;
    tile[rr + i * 16][cc4 + 3] = v.w;
  }
  __syncthreads();
  int r8 = (tid & 7) * 8;
  #pragma unroll
  for (int i = 0; i < 2; ++i) {
    int c = (tid >> 3) + i * 32;
    int co = c0 + c;
    int orow;
    if (split < 0) orow = co;
    else {
      int cl = co, o = base_off;
      if (cl >= split) { cl -= split; o += 128; }
      orow = ((cl >> 7) << 8) + o + (cl & 127);
    }
    bf16x8 v;
    #pragma unroll
    for (int j = 0; j < 8; ++j) v[j] = (bf16)tile[r8 + j][c];
    *(bf16x8*)&outm[(size_t)orow * R + r0 + r8] = v;
  }
}

// ---------------- zero small counters
__global__ void init_kernel(int* counts, int* fill) {
  int i = threadIdx.x;
  if (i < NE) { counts[i] = 0; fill[i] = 0; }
}

// ---------------- router: wave-per-token, fp64 logits, lane-parallel top-4, no atomics
__global__ __launch_bounds__(256) void router_kernel(const float* __restrict__ X,
                                                     const float* __restrict__ Wr,
                                                     const float* __restrict__ wgate,
                                                     bf16* __restrict__ Xbf,
                                                     float* __restrict__ topk_w,
                                                     int* __restrict__ topk_idx,
                                                     float* __restrict__ gate_sig) {
  const int wv = threadIdx.x >> 6, lane = threadIdx.x & 63;
  const int t = blockIdx.x * 4 + wv;
  const float* x = X + (size_t)t * H_DIM;
  float xf[32];
  #pragma unroll
  for (int j = 0; j < 32; ++j) xf[j] = x[j * 64 + lane];
  #pragma unroll
  for (int j = 0; j < 32; ++j) Xbf[(size_t)t * H_DIM + j * 64 + lane] = (bf16)xf[j];

  double lg = 0.0;
  for (int e = 0; e < NE + 1; ++e) {
    const float* w = (e < NE) ? (Wr + (size_t)e * H_DIM) : wgate;
    double s0 = 0.0, s1 = 0.0;
    #pragma unroll
    for (int j = 0; j < 32; j += 2) {
      s0 += (double)xf[j] * (double)w[j * 64 + lane];
      s1 += (double)xf[j + 1] * (double)w[(j + 1) * 64 + lane];
    }
    double s = s0 + s1;
    #pragma unroll
    for (int off = 32; off; off >>= 1) s += __shfl_xor(s, off);
    if (lane == e) lg = s;
  }

  double v = (lane < NE) ? lg : -1e300;
  double m = v;
  #pragma unroll
  for (int off = 32; off; off >>= 1) m = fmax(m, __shfl_xor(m, off));
  double ev = (lane < NE) ? exp(v - m) : 0.0;
  double den = ev;
  #pragma unroll
  for (int off = 32; off; off >>= 1) den += __shfl_xor(den, off);

  double vv = v;
  int widx = 0; double wval = 0.0;
  for (int k = 0; k < TOPK; ++k) {
    double bv = vv; int bi = lane;
    #pragma unroll
    for (int off = 32; off; off >>= 1) {
      double ov = __shfl_xor(bv, off);
      int oi = __shfl_xor(bi, off);
      if (ov > bv || (ov == bv && oi < bi)) { bv = ov; bi = oi; }
    }
    double evb = __shfl(ev, bi);
    if (lane == k) { widx = bi; wval = evb / den; }
    if (lane == bi) vv = -1e300;
  }
  if (lane < TOPK) {
    topk_idx[t * TOPK + lane] = widx;
    topk_w[t * TOPK + lane] = (float)wval;
  }
  if (lane == NE) gate_sig[t] = (float)(1.0 / (1.0 + exp(-lg)));
}

// ---------------- histogram (LDS-local, 16 atomics/block)
__global__ __launch_bounds__(256) void hist_kernel(const int* __restrict__ tidx,
                                                   int* __restrict__ counts) {
  __shared__ int h[NE];
  if (threadIdx.x < NE) h[threadIdx.x] = 0;
  __syncthreads();
  int gid = blockIdx.x * 256 + threadIdx.x;
  atomicAdd(&h[tidx[gid]], 1);
  __syncthreads();
  if (threadIdx.x < NE) atomicAdd(&counts[threadIdx.x], h[threadIdx.x]);
}

// ---------------- prefix scan + 256-row grouped tile table
__global__ void scan_kernel(const int* __restrict__ counts, int* __restrict__ offs,
                            int* __restrict__ fill, int* __restrict__ ttab,
                            int* __restrict__ ntl) {
  if (threadIdx.x != 0) return;
  int off = 0;
  for (int e = 0; e < NE; ++e) { offs[e] = off; off += counts[e]; fill[e] = 0; }
  offs[NE] = off;
  int n = 0;
  for (int e = 0; e < NE; ++e) {
    int cnt = counts[e], end_ = offs[e] + cnt;
    for (int m = 0; m < cnt; m += 256) {
      ttab[n * 3 + 0] = e;
      ttab[n * 3 + 1] = offs[e] + m;
      ttab[n * 3 + 2] = end_;
      ++n;
    }
  }
  *ntl = n;
}

// ---------------- scatter: hierarchical rank (ballot) + 16 atomics/block
__global__ __launch_bounds__(256) void scatter_kernel(const int* __restrict__ topk_idx,
                                                      const int* __restrict__ offs,
                                                      int* __restrict__ fill,
                                                      int* __restrict__ row_token,
                                                      int* __restrict__ row_pos) {
  __shared__ int wc[4][NE];
  __shared__ int wbase[4][NE];
  __shared__ int bbase[NE];
  const int tid = threadIdx.x, wv = tid >> 6, lane = tid & 63;
  const int gid = blockIdx.x * 256 + tid;
  const int e = topk_idx[gid];
  int rank = 0;
  #pragma unroll
  for (int ex = 0; ex < NE; ++ex) {
    unsigned long long b = __ballot(e == ex);
    if (e == ex) rank = __popcll(b & ((1ull << lane) - 1));
    if (lane == 0) wc[wv][ex] = __popcll(b);
  }
  __syncthreads();
  if (tid < NE) {
    int s = 0;
    #pragma unroll
    for (int w = 0; w < 4; ++w) { wbase[w][tid] = s; s += wc[w][tid]; }
    bbase[tid] = atomicAdd(&fill[tid], s);
  }
  __syncthreads();
  int pos = offs[e] + bbase[e] + wbase[wv][e] + rank;
  row_token[pos] = gid >> 2;
  row_pos[gid] = pos;
}

__device__ __forceinline__ void mfma_cluster(f32x4 (&a)[4][2], bf16x8 (&A)[4][2],
                                             bf16x8 (&B)[2][2]) {
  __builtin_amdgcn_s_setprio(1);
  #pragma unroll
  for (int m = 0; m < 4; ++m)
    #pragma unroll
    for (int n = 0; n < 2; ++n) {
      a[m][n] = __builtin_amdgcn_mfma_f32_16x16x32_bf16(A[m][0], B[n][0], a[m][n], 0, 0, 0);
      a[m][n] = __builtin_amdgcn_mfma_f32_16x16x32_bf16(A[m][1], B[n][1], a[m][n], 0, 0, 0);
    }
  __builtin_amdgcn_s_setprio(0);
}

struct GArgs {
  const bf16* A; const bf16* B; bf16* C;
  const int* row_token; const int* tile_tab; const int* n_tiles;
  size_t strideB;
  int lda, Ktot, ldc, Mdense, gx, gy;
};

// ---------------- 256x256 bf16 MFMA GEMM (R8-exact 16x16 schedule, 0-conflict
// LDS geometry). Two independent GEMMs merged per launch (block-id split).
__global__ __launch_bounds__(512, 2) void gemm256(GArgs ga, GArgs gb, int nblk0,
                                                  int fuse_swiglu) {
  GArgs g; int id;
  if ((int)blockIdx.x < nblk0) { g = ga; id = blockIdx.x; }
  else { g = gb; id = blockIdx.x - nblk0; }
  const int gx = g.gx, gy = g.gy;
  int mt, nt;
  if ((gx & 7) == 0) {          // mt-residue octave sweep (R8-best locality map)
    int oct = id / (8 * gy);
    int rem = id - oct * 8 * gy;
    mt = oct * 8 + (rem & 7);
    nt = rem >> 3;
  } else {
    mt = id % gx;
    nt = id / gx;
  }

  int e, row_start, row_end;
  if (g.tile_tab) {
    if (mt >= *g.n_tiles) return;
    e = g.tile_tab[mt * 3 + 0];
    row_start = g.tile_tab[mt * 3 + 1];
    row_end = g.tile_tab[mt * 3 + 2];
  } else {
    e = 0; row_start = mt * 256; row_end = g.Mdense;
  }
  const bf16* Ap = g.A;
  const bf16* Bp = g.B + (size_t)e * g.strideB;
  const int lda = g.lda, Ktot = g.Ktot, ldc = g.ldc;
  bf16* C = g.C;

  __shared__ bf16 smA[2][2][8192];   // [buf][half][128*64]
  __shared__ bf16 smB[2][2][8192];

  const int tid = threadIdx.x;
  const int wave = tid >> 6;
  const int lane = tid & 63;

  unsigned aoff[2][2], boff[2][2];
  {
    int csrc = (((tid & 7) ^ ((tid >> 3) & 7)) << 3);
    #pragma unroll
    for (int h = 0; h < 2; ++h)
      #pragma unroll
      for (int j = 0; j < 2; ++j) {
        int rho = j * 64 + (tid >> 3);
        int r = row_start + h * 128 + rho;
        if (r > row_end - 1) r = row_end - 1;
        int sr = g.row_token ? g.row_token[r] : r;
        aoff[h][j] = (unsigned)sr * (unsigned)lda + (unsigned)csrc;
        boff[h][j] = (unsigned)(nt * 256 + h * 128 + rho) * (unsigned)Ktot + (unsigned)csrc;
      }
  }

  auto STAGE_A = [&](int bufi, int h, int tt) {
    gload_lds16(Ap + (size_t)(aoff[h][0] + (unsigned)tt * 64u), &smA[bufi][h][wave << 9]);
    gload_lds16(Ap + (size_t)(aoff[h][1] + (unsigned)tt * 64u), &smA[bufi][h][4096 + (wave << 9)]);
  };
  auto STAGE_B = [&](int bufi, int h, int tt) {
    gload_lds16(Bp + (size_t)(boff[h][0] + (unsigned)tt * 64u), &smB[bufi][h][wave << 9]);
    gload_lds16(Bp + (size_t)(boff[h][1] + (unsigned)tt * 64u), &smB[bufi][h][4096 + (wave << 9)]);
  };

  const int warow = ((wave >> 2) << 6) + (lane & 15);
  const int wbrow = ((wave & 3) << 5) + (lane & 15);
  const int q4 = lane >> 4;
  auto LDA_ = [&](int bufi, int h, int m, int kk) -> bf16x8 {
    int row = warow + m * 16;
    int c = (kk * 4 + q4) ^ (row & 7);
    return *(const bf16x8*)&smA[bufi][h][row * 64 + c * 8];
  };
  auto LDB_ = [&](int bufi, int h, int n, int kk) -> bf16x8 {
    int row = wbrow + n * 16;
    int c = (kk * 4 + q4) ^ (row & 7);
    return *(const bf16x8*)&smB[bufi][h][row * 64 + c * 8];
  };

  f32x4 acc[4][4][2];
  #pragma unroll
  for (int q = 0; q < 4; ++q)
    #pragma unroll
    for (int m = 0; m < 4; ++m)
      #pragma unroll
      for (int n = 0; n < 2; ++n) acc[q][m][n] = (f32x4){0.f, 0.f, 0.f, 0.f};

  bf16x8 Ar[4][2], Br0[2][2], Br1[2][2];

#define RD_A(BUF, H) do { \
    _Pragma("unroll") for (int m_ = 0; m_ < 4; ++m_) { \
      Ar[m_][0] = LDA_(BUF, H, m_, 0); Ar[m_][1] = LDA_(BUF, H, m_, 1); } } while (0)
#define RD_B(BUF, H, DST) do { \
    _Pragma("unroll") for (int n_ = 0; n_ < 2; ++n_) { \
      DST[n_][0] = LDB_(BUF, H, n_, 0); DST[n_][1] = LDB_(BUF, H, n_, 1); } } while (0)

#define DO_TILE(CB, NB, TS) do { \
    /* f1: q0=(A0,B0); stage A0(NB); post-MFMA wait drains B1(CB) for f2 */ \
    RD_A(CB, 0); RD_B(CB, 0, Br0); \
    STAGE_A(NB, 0, TS); \
    BARRIER; \
    mfma_cluster(acc[0], Ar, Br0); \
    VMCNT4; \
    BARRIER; \
    /* f2: q1=(A0,B1); stage B0(NB); post-MFMA wait drains A1(CB) for f3 */ \
    RD_B(CB, 1, Br1); \
    STAGE_B(NB, 0, TS); \
    BARRIER; \
    mfma_cluster(acc[1], Ar, Br1); \
    VMCNT4; \
    BARRIER; \
    /* f3: q2=(A1,B1); stage B1(NB) */ \
    RD_A(CB, 1); \
    STAGE_B(NB, 1, TS); \
    BARRIER; \
    mfma_cluster(acc[2], Ar, Br1); \
    BARRIER; \
    /* f4: q3=(A1,B0); stage A1(NB); post-MFMA wait drains A0,B0(NB) for next f1 */ \
    STAGE_A(NB, 1, TS); \
    mfma_cluster(acc[3], Ar, Br0); \
    VMCNT4; \
    BARRIER; \
  } while (0)

  STAGE_A(0, 0, 0); STAGE_B(0, 0, 0); STAGE_B(0, 1, 0); STAGE_A(0, 1, 0);
  VMCNT4; BARRIER;

  const int nk = Ktot >> 6;
  for (int it = 0; it < nk; it += 2) {
    const int ts1 = it + 1;
    const int ts2 = (it + 2 < nk) ? it + 2 : it + 1;
    DO_TILE(0, 1, ts1);
    DO_TILE(1, 0, ts2);
  }
#undef DO_TILE
#undef RD_A
#undef RD_B

  const int er = (lane >> 4) * 4;
  if (fuse_swiglu) {
    const int cb0 = nt * 128 + ((wave & 3) << 5) + (lane & 15);
    #pragma unroll
    for (int qi = 0; qi < 2; ++qi) {
      const int qg = qi ? 3 : 0, qu = qi ? 2 : 1;
      int rb = row_start + qi * 128 + ((wave >> 2) << 6) + er;
      #pragma unroll
      for (int m = 0; m < 4; ++m)
        #pragma unroll
        for (int n = 0; n < 2; ++n)
          #pragma unroll
          for (int j = 0; j < 4; ++j) {
            int r = rb + m * 16 + j;
            if (r < row_end) {
              float g0 = acc[qg][m][n][j];
              float u0 = acc[qu][m][n][j];
              float s = g0 / (1.f + __expf(-g0));
              C[(size_t)r * ldc + cb0 + n * 16] = (bf16)(s * u0);
            }
          }
    }
  } else {
    const int qr[4] = {0, 0, 1, 1}, qc[4] = {0, 1, 1, 0};
    #pragma unroll
    for (int q = 0; q < 4; ++q) {
      int rb = row_start + qr[q] * 128 + ((wave >> 2) << 6) + er;
      int cb0 = nt * 256 + qc[q] * 128 + ((wave & 3) << 5) + (lane & 15);
      #pragma unroll
      for (int m = 0; m < 4; ++m)
        #pragma unroll
        for (int n = 0; n < 2; ++n)
          #pragma unroll
          for (int j = 0; j < 4; ++j) {
            int r = rb + m * 16 + j;
            if (r < row_end) C[(size_t)r * ldc + cb0 + n * 16] = (bf16)acc[q][m][n][j];
          }
    }
  }
}

// ---------------- combine
__global__ __launch_bounds__(256) void combine_kernel(const float* __restrict__ topk_w,
                                                      const int* __restrict__ row_pos,
                                                      const bf16* __restrict__ eout,
                                                      const bf16* __restrict__ shout,
                                                      const float* __restrict__ gate_sig,
                                                      float* __restrict__ out) {
  int t = blockIdx.x;
  float w0 = topk_w[t * 4 + 0], w1 = topk_w[t * 4 + 1];
  float w2 = topk_w[t * 4 + 2], w3 = topk_w[t * 4 + 3];
  size_t p0 = (size_t)row_pos[t * 4 + 0] * H_DIM;
  size_t p1 = (size_t)row_pos[t * 4 + 1] * H_DIM;
  size_t p2 = (size_t)row_pos[t * 4 + 2] * H_DIM;
  size_t p3 = (size_t)row_pos[t * 4 + 3] * H_DIM;
  float g = gate_sig[t];
  size_t tb = (size_t)t * H_DIM;
  size_t hb = (size_t)threadIdx.x * 8;
  bf16x8 a0 = *(const bf16x8*)&eout[p0 + hb];
  bf16x8 a1 = *(const bf16x8*)&eout[p1 + hb];
  bf16x8 a2 = *(const bf16x8*)&eout[p2 + hb];
  bf16x8 a3 = *(const bf16x8*)&eout[p3 + hb];
  bf16x8 sh = *(const bf16x8*)&shout[tb + hb];
  float r[8];
  #pragma unroll
  for (int j = 0; j < 8; ++j)
    r[j] = w0 * (float)a0[j] + w1 * (float)a1[j] + w2 * (float)a2[j]
         + w3 * (float)a3[j] + g * (float)sh[j];
  float4 o0 = {r[0], r[1], r[2], r[3]}, o1 = {r[4], r[5], r[6], r[7]};
  *(float4*)&out[tb + hb] = o0;
  *(float4*)&out[tb + hb + 4] = o1;
}

extern "C" void kernel_launch(void* const* d_in, const int* in_sizes, int n_in,
                              void* d_out, int out_size, void* d_ws, size_t ws_size,
                              hipStream_t stream) {
  const float* X   = (const float*)d_in[0];
  const float* Wr  = (const float*)d_in[1];
  const float* Wgu = (const float*)d_in[2];
  const float* Wd  = (const float*)d_in[3];
  const float* Wsg = (const float*)d_in[4];
  const float* Wsu = (const float*)d_in[5];
  const float* Wsd = (const float*)d_in[6];
  const float* Wge = (const float*)d_in[7];
  float* out = (float*)d_out;

  size_t off = 0;
  auto alloc = [&](size_t bytes) -> void* {
    void* p = (char*)d_ws + off;
    off += (bytes + 255) & ~(size_t)255;
    return p;
  };
  bf16* Xbf    = (bf16*)alloc((size_t)T_TOK * H_DIM * 2);
  bf16* WguT   = (bf16*)alloc((size_t)NE * 2 * IMOE * H_DIM * 2);
  bf16* WdT    = (bf16*)alloc((size_t)NE * H_DIM * IMOE * 2);
  bf16* WsguT  = (bf16*)alloc((size_t)2 * ISH * H_DIM * 2);
  bf16* WsdT   = (bf16*)alloc((size_t)H_DIM * ISH * 2);
  bf16* act    = (bf16*)alloc((size_t)TK * IMOE * 2);
  bf16* act_sh = (bf16*)alloc((size_t)T_TOK * ISH * 2);
  bf16* eout   = (bf16*)alloc((size_t)TK * H_DIM * 2);
  bf16* shout  = (bf16*)alloc((size_t)T_TOK * H_DIM * 2);
  float* tw    = (float*)alloc((size_t)T_TOK * TOPK * 4);
  int*   tidx  = (int*)alloc((size_t)T_TOK * TOPK * 4);
  float* gsig  = (float*)alloc((size_t)T_TOK * 4);
  int*   counts= (int*)alloc(64);
  int*   offs  = (int*)alloc(128);
  int*   fill  = (int*)alloc(64);
  int*   rowtok= (int*)alloc((size_t)TK * 4);
  int*   rowpos= (int*)alloc((size_t)TK * 4);
  int*   ttab  = (int*)alloc((size_t)MAXT256 * 3 * 4);
  int*   ntl   = (int*)alloc(64);
  if (off > ws_size) return;

  init_kernel<<<1, 32, 0, stream>>>(counts, fill);

  cvt_transpose64<<<dim3(H_DIM / 64, ISH / 64, 1), 256, 0, stream>>>(
      Wsd, WsdT, ISH, H_DIM, 0, 0, -1, 0);
  cvt_transpose64<<<dim3(ISH / 64, H_DIM / 64, 1), 256, 0, stream>>>(
      Wsg, WsguT, H_DIM, ISH, 0, 0, ISH, 0);
  cvt_transpose64<<<dim3(ISH / 64, H_DIM / 64, 1), 256, 0, stream>>>(
      Wsu, WsguT, H_DIM, ISH, 0, 0, ISH, 128);
  cvt_transpose64<<<dim3(H_DIM / 64, IMOE / 64, NE), 256, 0, stream>>>(
      Wd, WdT, IMOE, H_DIM, (size_t)IMOE * H_DIM, (size_t)IMOE * H_DIM, -1, 0);
  cvt_transpose64<<<dim3(2 * IMOE / 64, H_DIM / 64, NE), 256, 0, stream>>>(
      Wgu, WguT, H_DIM, 2 * IMOE, (size_t)H_DIM * 2 * IMOE, (size_t)H_DIM * 2 * IMOE, IMOE, 0);

  router_kernel<<<T_TOK / 4, 256, 0, stream>>>(X, Wr, Wge, Xbf, tw, tidx, gsig);
  hist_kernel<<<TK / 256, 256, 0, stream>>>(tidx, counts);
  scan_kernel<<<1, 64, 0, stream>>>(counts, offs, fill, ttab, ntl);
  scatter_kernel<<<TK / 256, 256, 0, stream>>>(tidx, offs, fill, rowtok, rowpos);

  // Launch 1 (fused swiglu): grouped gate_up || dense shared gate_up (share A=Xbf)
  GArgs g1;
  g1.A = Xbf; g1.B = WguT; g1.C = act;
  g1.row_token = rowtok; g1.tile_tab = ttab; g1.n_tiles = ntl;
  g1.strideB = (size_t)2 * IMOE * H_DIM;
  g1.lda = H_DIM; g1.Ktot = H_DIM; g1.ldc = IMOE; g1.Mdense = 0;
  g1.gx = MAXT256; g1.gy = 2 * IMOE / 256;          // 144 x 11
  GArgs gsg;
  gsg.A = Xbf; gsg.B = WsguT; gsg.C = act_sh;
  gsg.row_token = nullptr; gsg.tile_tab = nullptr; gsg.n_tiles = nullptr;
  gsg.strideB = 0;
  gsg.lda = H_DIM; gsg.Ktot = H_DIM; gsg.ldc = ISH; gsg.Mdense = T_TOK;
  gsg.gx = T_TOK / 256; gsg.gy = 2 * ISH / 256;     // 32 x 44
  int nb1 = g1.gx * g1.gy;
  gemm256<<<nb1 + gsg.gx * gsg.gy, 512, 0, stream>>>(g1, gsg, nb1, 1);

  // Launch 2 (plain): grouped down || dense shared down
  GArgs g2;
  g2.A = act; g2.B = WdT; g2.C = eout;
  g2.row_token = nullptr; g2.tile_tab = ttab; g2.n_tiles = ntl;
  g2.strideB = (size_t)H_DIM * IMOE;
  g2.lda = IMOE; g2.Ktot = IMOE; g2.ldc = H_DIM; g2.Mdense = 0;
  g2.gx = MAXT256; g2.gy = H_DIM / 256;             // 144 x 8
  GArgs gsd;
  gsd.A = act_sh; gsd.B = WsdT; gsd.C = shout;
  gsd.row_token = nullptr; gsd.tile_tab = nullptr; gsd.n_tiles = nullptr;
  gsd.strideB = 0;
  gsd.lda = ISH; gsd.Ktot = ISH; gsd.ldc = H_DIM; gsd.Mdense = T_TOK;
  gsd.gx = T_TOK / 256; gsd.gy = H_DIM / 256;       // 32 x 8
  int nb2 = g2.gx * g2.gy;
  gemm256<<<nb2 + gsd.gx * gsd.gy, 512, 0, stream>>>(g2, gsd, nb2, 0);

  combine_kernel<<<T_TOK, 256, 0, stream>>>(tw, rowpos, eout, shout, gsig, out);
}